// Round 14
// baseline (209.844 us; speedup 1.0000x reference)
//
#include <hip/hip_runtime.h>

#define HF 64
#define WF 64
#define CCH 512

typedef float f32x4 __attribute__((ext_vector_type(4)));

// f32 -> bf16 round-to-nearest-even
__device__ __forceinline__ unsigned short f32_to_bf16(float f) {
    unsigned int x = __float_as_uint(f);
    unsigned int r = (x + 0x7FFFu + ((x >> 16) & 1u)) >> 16;
    return (unsigned short)r;
}
__device__ __forceinline__ float bf16_to_f32(unsigned short u) {
    return __uint_as_float(((unsigned int)u) << 16);
}

// ---------------- transpose+convert NCHW f32 -> NHWC bf16 -------------------
__global__ __launch_bounds__(256) void nchw_to_nhwc_bf16(const float* __restrict__ src,
                                                         unsigned short* __restrict__ dst) {
    __shared__ float tile[32][33];
    const int hw0 = blockIdx.x * 32;
    const int c0  = blockIdx.y * 32;
    const int b   = blockIdx.z;
    const int tx  = threadIdx.x & 31;
    const int ty  = threadIdx.x >> 5;   // 0..7
    const float*    s = src + (size_t)b * CCH * (HF * WF);
    unsigned short* d = dst + (size_t)b * (HF * WF) * CCH;
#pragma unroll
    for (int i = 0; i < 32; i += 8)
        tile[ty + i][tx] = s[(size_t)(c0 + ty + i) * (HF * WF) + hw0 + tx];
    __syncthreads();
#pragma unroll
    for (int i = 0; i < 32; i += 8)
        d[(size_t)(hw0 + ty + i) * CCH + c0 + tx] = f32_to_bf16(tile[tx][ty + i]);
}

// ---------------- per-wave worker: sample rows [I0, I1) ---------------------
// Horizontal interp hoisted to row-load time (same FMA expression as before,
// computed once per loaded feature row instead of once per sample row:
// bitwise-identical results, ~half the VALU, half the row-cache registers).
template <int I0, int I1>
__device__ __forceinline__ void roi_part(const unsigned short* __restrict__ ft,
                                         float* __restrict__ srow,
                                         float x1, float y1, float bin_h, float bin_w,
                                         unsigned bBase, int c) {
    float wr_[8], fvw[8]; unsigned colc[8];
#pragma unroll
    for (int j = 0; j < 8; ++j) {
        float w  = x1 + (float)j * bin_w;
        float ws = fminf(floorf(w), 62.0f);
        wr_[j]   = w - ws;
        int   wi = (int)fminf(fmaxf(ws, 0.0f), 62.0f);
        fvw[j]   = (w >= 0.0f && w < 64.0f) ? 1.0f : 0.0f;
        colc[j]  = (unsigned)(wi * CCH + c);
    }

    float rowT[8], rowB[8];   // horizontally-interpolated feature rows rr, rr+1
    int   curR = -1000;
    float prev[8];

#pragma unroll
    for (int i = I0; i < I1; ++i) {
        float h  = y1 + (float)i * bin_h;
        float hs = fminf(floorf(h), 62.0f);
        float hr = h - hs;
        int   rr = (int)fminf(fmaxf(hs, 0.0f), 62.0f);
        float fh = (h >= 0.0f && h < 64.0f) ? 1.0f : 0.0f;

        if (rr == curR) {
            // both interp rows cached
        } else if (rr == curR + 1) {
#pragma unroll
            for (int j = 0; j < 8; ++j) rowT[j] = rowB[j];
            const unsigned rb = bBase + (unsigned)((rr + 1) * WF * CCH);
#pragma unroll
            for (int j = 0; j < 8; ++j) {
                const float L = bf16_to_f32(ft[rb + colc[j]]);
                const float R = bf16_to_f32(ft[rb + colc[j] + CCH]);
                rowB[j] = L + wr_[j] * (R - L);
            }
        } else {
            const unsigned rt = bBase + (unsigned)(rr * WF * CCH);
            const unsigned rb = rt + (unsigned)(WF * CCH);
#pragma unroll
            for (int j = 0; j < 8; ++j) {
                const float L = bf16_to_f32(ft[rt + colc[j]]);
                const float R = bf16_to_f32(ft[rt + colc[j] + CCH]);
                rowT[j] = L + wr_[j] * (R - L);
            }
#pragma unroll
            for (int j = 0; j < 8; ++j) {
                const float L = bf16_to_f32(ft[rb + colc[j]]);
                const float R = bf16_to_f32(ft[rb + colc[j] + CCH]);
                rowB[j] = L + wr_[j] * (R - L);
            }
        }
        curR = rr;

        float cur[8];
#pragma unroll
        for (int j = 0; j < 8; ++j) {
            const float v = rowT[j] + hr * (rowB[j] - rowT[j]);
            cur[j] = v * (fh * fvw[j]);
        }
        if (i > I0) {
#pragma unroll
            for (int j = 0; j < 7; ++j)
                srow[(i - 1) * 7 + j] =
                    0.25f * (prev[j] + prev[j + 1] + cur[j] + cur[j + 1]);
        }
#pragma unroll
        for (int j = 0; j < 8; ++j) prev[j] = cur[j];
    }
}

// ---------------- main RoIAlign+avg kernel (row-split, 2 waves/item) --------
// LEDGER of hard-won constraints:
//  - R5: NEVER stage output as bf16 in LDS (73->444us, mechanism unknown).
//  - R8: stores MUST be full-line wave-contiguous (scalar stores -> RFO 195us).
//  - R12: NEVER dynamic-steal off one global atomic counter (240us).
//  - Falsified: byte-cuts beyond R10, channel-axis occupancy (R8), de-phasing
//    (R9), ILP prefetch (R11), persistence (R13). Keep: R10 dedup, R7 nt.
// R14: split the SAMPLE-ROW axis across 2 waves sharing one 64ch x 49 LDS
// tile (12.25KB/block -> ~12 blocks/CU): per-wave gather chain halves AND
// waves/CU rises; store path byte-identical to R10.
__global__ __launch_bounds__(128, 6) void roialign_split(const unsigned short* __restrict__ ft,
                                                         const float* __restrict__ rois,
                                                         float* __restrict__ out) {
    __shared__ __align__(16) float sbuf[64 * 49];
    const int tid  = threadIdx.x;
    const int lane = tid & 63;
    const int wid  = tid >> 6;          // 0 or 1
    const int blk  = blockIdx.x;
    const int k    = blk >> 3;          // roi
    const int sub  = blk & 7;           // 64-channel group
    const int c    = sub * 64 + lane;

    const float* r = rois + (size_t)k * 5;
    const int   b  = (int)r[0];
    const float x1 = r[1] * 0.0625f;
    const float y1 = r[2] * 0.0625f;
    const float x2 = r[3] * 0.0625f;
    const float y2 = r[4] * 0.0625f;
    const float bin_h = fmaxf(y2 - y1, 0.0f) / 7.0f;
    const float bin_w = fmaxf(x2 - x1, 0.0f) / 7.0f;
    const unsigned bBase = (unsigned)(b * HF * WF * CCH);

    float* srow = sbuf + lane * 49;

    // wave 0: samples 0..3 -> out rows 0..2 (srow[0..20])
    // wave 1: samples 3..7 -> out rows 3..6 (srow[21..48])
    if (wid == 0) roi_part<0, 4>(ft, srow, x1, y1, bin_h, bin_w, bBase, c);
    else          roi_part<3, 8>(ft, srow, x1, y1, bin_h, bin_w, bBase, c);

    __syncthreads();

    // coalesced nt writeout: 64ch x 49 f32 = 784 f32x4 (196 full lines)
    float* obase = out + ((size_t)k * CCH + (size_t)sub * 64) * 49;
    const f32x4* s4 = reinterpret_cast<const f32x4*>(sbuf);
    f32x4*       o4 = reinterpret_cast<f32x4*>(obase);
    for (int idx = tid; idx < 784; idx += 128)
        __builtin_nontemporal_store(s4[idx], &o4[idx]);
}

// ---------------- fallback: direct NCHW f32 (if ws too small) ---------------
__global__ __launch_bounds__(256) void roialign_f32_nchw(const float* __restrict__ ft,
                                                         const float* __restrict__ rois,
                                                         float* __restrict__ out) {
    __shared__ __align__(16) float sbuf[256 * 49];
    const int blk   = blockIdx.x;
    const int k     = blk >> 1;
    const int chunk = blk & 1;
    const int tid   = threadIdx.x;
    const int c     = chunk * 256 + tid;

    const float* r = rois + (size_t)k * 5;
    const int   b  = (int)r[0];
    const float x1 = r[1] * 0.0625f;
    const float y1 = r[2] * 0.0625f;
    const float x2 = r[3] * 0.0625f;
    const float y2 = r[4] * 0.0625f;
    const float bin_h = fmaxf(y2 - y1, 0.0f) / 7.0f;
    const float bin_w = fmaxf(x2 - x1, 0.0f) / 7.0f;

    int hi_[8]; float hr_[8]; float fvh[8];
    int wi_[8]; float wr_[8]; float fvw[8];
#pragma unroll
    for (int i = 0; i < 8; ++i) {
        float h  = y1 + (float)i * bin_h;
        float hs = fminf(floorf(h), 62.0f);
        hr_[i] = h - hs;
        hi_[i] = (int)fminf(fmaxf(hs, 0.0f), 62.0f);
        fvh[i] = (h >= 0.0f && h < 64.0f) ? 1.0f : 0.0f;
        float w  = x1 + (float)i * bin_w;
        float ws = fminf(floorf(w), 62.0f);
        wr_[i] = w - ws;
        wi_[i] = (int)fminf(fmaxf(ws, 0.0f), 62.0f);
        fvw[i] = (w >= 0.0f && w < 64.0f) ? 1.0f : 0.0f;
    }

    float prev[8];
    float* srow = sbuf + tid * 49;
#pragma unroll
    for (int i = 0; i < 8; ++i) {
        float cur[8];
#pragma unroll
        for (int j = 0; j < 8; ++j) {
            size_t o00 = (size_t)(b * CCH + c) * (HF * WF) + hi_[i] * WF + wi_[j];
            const float v00 = ft[o00];
            const float v01 = ft[o00 + 1];
            const float v10 = ft[o00 + WF];
            const float v11 = ft[o00 + WF + 1];
            const float top = v00 + wr_[j] * (v01 - v00);
            const float bot = v10 + wr_[j] * (v11 - v10);
            const float v   = top + hr_[i] * (bot - top);
            cur[j] = v * (fvh[i] * fvw[j]);
        }
        if (i > 0) {
#pragma unroll
            for (int j = 0; j < 7; ++j)
                srow[(i - 1) * 7 + j] =
                    0.25f * (prev[j] + prev[j + 1] + cur[j] + cur[j + 1]);
        }
#pragma unroll
        for (int j = 0; j < 8; ++j) prev[j] = cur[j];
    }
    __syncthreads();
    float* obase = out + ((size_t)k * CCH + (size_t)chunk * 256) * 49;
    const f32x4* s4 = reinterpret_cast<const f32x4*>(sbuf);
    f32x4*       o4 = reinterpret_cast<f32x4*>(obase);
    for (int idx = tid; idx < 3136; idx += 256) o4[idx] = s4[idx];
}

extern "C" void kernel_launch(void* const* d_in, const int* in_sizes, int n_in,
                              void* d_out, int out_size, void* d_ws, size_t ws_size,
                              hipStream_t stream) {
    const float* feat = (const float*)d_in[0];
    const float* rois = (const float*)d_in[1];
    float*       out  = (float*)d_out;

    const int B = in_sizes[0] / (CCH * HF * WF);
    const int K = in_sizes[1] / 5;

    const size_t featBytes = (size_t)B * CCH * HF * WF * sizeof(unsigned short);
    if (ws_size >= featBytes) {
        unsigned short* ftr = (unsigned short*)d_ws;
        dim3 tg((HF * WF) / 32, CCH / 32, B);
        nchw_to_nhwc_bf16<<<tg, 256, 0, stream>>>(feat, ftr);
        roialign_split<<<K * 8, 128, 0, stream>>>(ftr, rois, out);
    } else {
        roialign_f32_nchw<<<K * 2, 256, 0, stream>>>(feat, rois, out);
    }
}

// Round 15
// 66.168 us; speedup vs baseline: 3.1714x; 3.1714x over previous
//
#include <hip/hip_runtime.h>

#define HF 64
#define WF 64
#define CCH 512

typedef float f32x4 __attribute__((ext_vector_type(4)));

// f32 -> bf16 round-to-nearest-even
__device__ __forceinline__ unsigned short f32_to_bf16(float f) {
    unsigned int x = __float_as_uint(f);
    unsigned int r = (x + 0x7FFFu + ((x >> 16) & 1u)) >> 16;
    return (unsigned short)r;
}
__device__ __forceinline__ float bf16_to_f32(unsigned short u) {
    return __uint_as_float(((unsigned int)u) << 16);
}

// ---------------- transpose+convert NCHW f32 -> NHWC bf16 -------------------
__global__ __launch_bounds__(256) void nchw_to_nhwc_bf16(const float* __restrict__ src,
                                                         unsigned short* __restrict__ dst) {
    __shared__ float tile[32][33];
    const int hw0 = blockIdx.x * 32;
    const int c0  = blockIdx.y * 32;
    const int b   = blockIdx.z;
    const int tx  = threadIdx.x & 31;
    const int ty  = threadIdx.x >> 5;   // 0..7
    const float*    s = src + (size_t)b * CCH * (HF * WF);
    unsigned short* d = dst + (size_t)b * (HF * WF) * CCH;
#pragma unroll
    for (int i = 0; i < 32; i += 8)
        tile[ty + i][tx] = s[(size_t)(c0 + ty + i) * (HF * WF) + hw0 + tx];
    __syncthreads();
#pragma unroll
    for (int i = 0; i < 32; i += 8)
        d[(size_t)(hw0 + ty + i) * CCH + c0 + tx] = f32_to_bf16(tile[tx][ty + i]);
}

// ---------------- main RoIAlign+avg kernel (NHWC bf16 gather) ---------------
// FINAL CONFIGURATION (= R10, session best 66.7us). LEDGER:
//  - R5: NEVER stage output as bf16 in LDS (73->444us).
//  - R8: stores MUST be full-line wave-contiguous from a big f32 LDS tile;
//    scalar 196B-stride stores -> RFO, FETCH 114MB, 195us.
//  - R14: 12.25KB-tile/2-wave variant -> WRITE 522MB (2.66x amplification),
//    209us. The 256-thread/50KB-tile/392-line writeout is the only shape
//    with clean 196MB writes.
//  - R12: dynamic stealing off one atomic counter -> 240us. Static only.
//  - Falsified as neutral: nt-store L2 theory (R7), occupancy/direct (R8),
//    de-phasing (R9), scalarize+ILP-prefetch (R11), persistence (R13).
//  - Kept wins: NHWC transpose (R0), bf16 features (R2), 128-tile+row-reuse
//    dedup (R10), wave-private barrier-free writeout (R9), nt stores (R7).
__global__ __launch_bounds__(256) void roialign_bf16(const unsigned short* __restrict__ ft,
                                                     const float* __restrict__ rois,
                                                     float* __restrict__ out) {
    __shared__ __align__(16) float sbuf[256 * 49];

    const int blk   = blockIdx.x;
    const int k     = blk >> 1;
    const int chunk = blk & 1;
    const int tid   = threadIdx.x;
    const int c     = chunk * 256 + tid;

    const float* r = rois + (size_t)k * 5;
    const int   b  = (int)r[0];
    const float x1 = r[1] * 0.0625f;
    const float y1 = r[2] * 0.0625f;
    const float x2 = r[3] * 0.0625f;
    const float y2 = r[4] * 0.0625f;
    const float bin_h = fmaxf(y2 - y1, 0.0f) / 7.0f;
    const float bin_w = fmaxf(x2 - x1, 0.0f) / 7.0f;

    int   hi_[8]; float hr_[8]; float fvh[8];
    int   wi_[8]; float wr_[8]; float fvw[8];
    unsigned colc[8];
#pragma unroll
    for (int i = 0; i < 8; ++i) {
        float h  = y1 + (float)i * bin_h;
        float hs = fminf(floorf(h), 62.0f);
        hr_[i]   = h - hs;
        hi_[i]   = (int)fminf(fmaxf(hs, 0.0f), 62.0f);
        fvh[i]   = (h >= 0.0f && h < 64.0f) ? 1.0f : 0.0f;
        float w  = x1 + (float)i * bin_w;
        float ws = fminf(floorf(w), 62.0f);
        wr_[i]   = w - ws;
        wi_[i]   = (int)fminf(fmaxf(ws, 0.0f), 62.0f);
        fvw[i]   = (w >= 0.0f && w < 64.0f) ? 1.0f : 0.0f;
        colc[i]  = (unsigned)(wi_[i] * CCH + c);
    }
    const unsigned bBase = (unsigned)(b * HF * WF * CCH);

    // corner-row register caches: T = feature row hi_[i], B = row hi_[i]+1
    float TL[8], TR[8], BL[8], BR[8];
    int curR = -1000;

    float  prev[8];
    float* srow = sbuf + tid * 49;

#pragma unroll
    for (int i = 0; i < 8; ++i) {
        const int rr = hi_[i];
        if (rr == curR) {
            // both rows cached — no loads
        } else if (rr == curR + 1) {
            // shift: old bottom row becomes top; load one new row
#pragma unroll
            for (int j = 0; j < 8; ++j) { TL[j] = BL[j]; TR[j] = BR[j]; }
            const unsigned rb = bBase + (unsigned)((rr + 1) * WF * CCH);
#pragma unroll
            for (int j = 0; j < 8; ++j) {
                BL[j] = bf16_to_f32(ft[rb + colc[j]]);
                BR[j] = bf16_to_f32(ft[rb + colc[j] + CCH]);
            }
        } else {
            const unsigned rt = bBase + (unsigned)(rr * WF * CCH);
            const unsigned rb = rt + (unsigned)(WF * CCH);
#pragma unroll
            for (int j = 0; j < 8; ++j) {
                TL[j] = bf16_to_f32(ft[rt + colc[j]]);
                TR[j] = bf16_to_f32(ft[rt + colc[j] + CCH]);
            }
#pragma unroll
            for (int j = 0; j < 8; ++j) {
                BL[j] = bf16_to_f32(ft[rb + colc[j]]);
                BR[j] = bf16_to_f32(ft[rb + colc[j] + CCH]);
            }
        }
        curR = rr;

        float cur[8];
#pragma unroll
        for (int j = 0; j < 8; ++j) {
            const float top = TL[j] + wr_[j] * (TR[j] - TL[j]);
            const float bot = BL[j] + wr_[j] * (BR[j] - BL[j]);
            const float v   = top + hr_[i] * (bot - top);
            cur[j] = v * (fvh[i] * fvw[j]);
        }
        if (i > 0) {
#pragma unroll
            for (int j = 0; j < 7; ++j)
                srow[(i - 1) * 7 + j] =
                    0.25f * (prev[j] + prev[j + 1] + cur[j] + cur[j + 1]);
        }
#pragma unroll
        for (int j = 0; j < 8; ++j) prev[j] = cur[j];
    }

    // Wave-private writeout (R9): no __syncthreads; wave w reads back only
    // its own LDS quarter. wave_barrier pins ordering for the compiler.
    __builtin_amdgcn_wave_barrier();

    const int wid  = tid >> 6;
    const int lane = tid & 63;
    float* obase = out + ((size_t)k * CCH + (size_t)chunk * 256 + (size_t)wid * 64) * 49;
    const f32x4* s4 = reinterpret_cast<const f32x4*>(sbuf + (size_t)wid * 64 * 49);
    f32x4*       o4 = reinterpret_cast<f32x4*>(obase);
    // 64 ch * 49 f32 = 784 f32x4 per wave
    for (int idx = lane; idx < 784; idx += 64)
        __builtin_nontemporal_store(s4[idx], &o4[idx]);
}

// ---------------- fallback: direct NCHW f32 (if ws too small) ---------------
__global__ __launch_bounds__(256) void roialign_f32_nchw(const float* __restrict__ ft,
                                                         const float* __restrict__ rois,
                                                         float* __restrict__ out) {
    __shared__ __align__(16) float sbuf[256 * 49];
    const int blk   = blockIdx.x;
    const int k     = blk >> 1;
    const int chunk = blk & 1;
    const int tid   = threadIdx.x;
    const int c     = chunk * 256 + tid;

    const float* r = rois + (size_t)k * 5;
    const int   b  = (int)r[0];
    const float x1 = r[1] * 0.0625f;
    const float y1 = r[2] * 0.0625f;
    const float x2 = r[3] * 0.0625f;
    const float y2 = r[4] * 0.0625f;
    const float bin_h = fmaxf(y2 - y1, 0.0f) / 7.0f;
    const float bin_w = fmaxf(x2 - x1, 0.0f) / 7.0f;

    int hi_[8]; float hr_[8]; float fvh[8];
    int wi_[8]; float wr_[8]; float fvw[8];
#pragma unroll
    for (int i = 0; i < 8; ++i) {
        float h  = y1 + (float)i * bin_h;
        float hs = fminf(floorf(h), 62.0f);
        hr_[i] = h - hs;
        hi_[i] = (int)fminf(fmaxf(hs, 0.0f), 62.0f);
        fvh[i] = (h >= 0.0f && h < 64.0f) ? 1.0f : 0.0f;
        float w  = x1 + (float)i * bin_w;
        float ws = fminf(floorf(w), 62.0f);
        wr_[i] = w - ws;
        wi_[i] = (int)fminf(fmaxf(ws, 0.0f), 62.0f);
        fvw[i] = (w >= 0.0f && w < 64.0f) ? 1.0f : 0.0f;
    }

    float prev[8];
    float* srow = sbuf + tid * 49;
#pragma unroll
    for (int i = 0; i < 8; ++i) {
        float cur[8];
#pragma unroll
        for (int j = 0; j < 8; ++j) {
            size_t o00 = (size_t)(b * CCH + c) * (HF * WF) + hi_[i] * WF + wi_[j];
            const float v00 = ft[o00];
            const float v01 = ft[o00 + 1];
            const float v10 = ft[o00 + WF];
            const float v11 = ft[o00 + WF + 1];
            const float top = v00 + wr_[j] * (v01 - v00);
            const float bot = v10 + wr_[j] * (v11 - v10);
            const float v   = top + hr_[i] * (bot - top);
            cur[j] = v * (fvh[i] * fvw[j]);
        }
        if (i > 0) {
#pragma unroll
            for (int j = 0; j < 7; ++j)
                srow[(i - 1) * 7 + j] =
                    0.25f * (prev[j] + prev[j + 1] + cur[j] + cur[j + 1]);
        }
#pragma unroll
        for (int j = 0; j < 8; ++j) prev[j] = cur[j];
    }
    __syncthreads();
    float* obase = out + ((size_t)k * CCH + (size_t)chunk * 256) * 49;
    const f32x4* s4 = reinterpret_cast<const f32x4*>(sbuf);
    f32x4*       o4 = reinterpret_cast<f32x4*>(obase);
    for (int idx = tid; idx < 3136; idx += 256) o4[idx] = s4[idx];
}

extern "C" void kernel_launch(void* const* d_in, const int* in_sizes, int n_in,
                              void* d_out, int out_size, void* d_ws, size_t ws_size,
                              hipStream_t stream) {
    const float* feat = (const float*)d_in[0];
    const float* rois = (const float*)d_in[1];
    float*       out  = (float*)d_out;

    const int B = in_sizes[0] / (CCH * HF * WF);
    const int K = in_sizes[1] / 5;

    const size_t tbytes = (size_t)B * CCH * HF * WF * sizeof(unsigned short);
    if (ws_size >= tbytes) {
        unsigned short* ftr = (unsigned short*)d_ws;
        dim3 tg((HF * WF) / 32, CCH / 32, B);
        nchw_to_nhwc_bf16<<<tg, 256, 0, stream>>>(feat, ftr);
        roialign_bf16<<<K * 2, 256, 0, stream>>>(ftr, rois, out);
    } else {
        roialign_f32_nchw<<<K * 2, 256, 0, stream>>>(feat, rois, out);
    }
}